// Round 10
// baseline (258.914 us; speedup 1.0000x reference)
//
#include <hip/hip_runtime.h>
#include <hip/hip_bf16.h>

typedef short s8v __attribute__((ext_vector_type(8)));
typedef float f4v __attribute__((ext_vector_type(4)));

#define DEV __device__ __forceinline__
#define LOG2E 1.4426950408889634f

DEV unsigned short f2b(float f) {
  unsigned u = __builtin_bit_cast(unsigned, f);
  u += 0x7FFFu + ((u >> 16) & 1u);
  return (unsigned short)(u >> 16);
}
DEV float b2f(unsigned short s) {
  unsigned u = ((unsigned)s) << 16;
  return __builtin_bit_cast(float, u);
}
DEV float sigf(float x) { return __builtin_amdgcn_rcpf(1.f + __expf(-x)); }

// ---------------- workspace layout (bytes, all 256-aligned) ----------------
#define O_WHH0  0u          // 131072  bf16 frag-packed whh0
#define O_WHH1  131072u     // 131072
#define O_WIH0  262144u     // 65536
#define O_WIH1  327680u     // 131072
#define O_B0    458752u     // 2048    f32 permuted bih0+bhh0
#define O_B1    460800u     // 2048
#define O_W1F   475392u     // 57344   bf16 head-W1 MFMA frags: [nt14][kt4][l64][j8]
#define O_DP2T  532736u     // 6656    f32 (dp2|cp2|pc2 contiguous)
#define O_FEATS 4733696u    // 33554432 bf16 feats [b*32+t][64] natural
#define O_Y0    38288128u   // 67108864 bf16 y0    [blk][t][row32][128]

// ---------------- LDS pool (147456 B) ----------------
// Passes: sWhh @ 0 (131072), sH0 @ 131072 (8192), sH1 @ 139264 (8192)
#define P_WHH   0
#define P_H0    131072
#define P_H1    139264
#define P_TOT   147456
// Heads phase (aliases 0..131072 after passes; sH0 @131072 preserved = h(31)):
#define P_HMID  0        // 29184  f32 smid[32][228]
#define P_HW2   29696    // 6656   f32 w2
#define P_HPC   36864    // 512    f32 pre-softmax

// Column permutation: reordered col c (0..511) -> orig gate-major row of W.
DEV int orig_col(int c) { return 128 * ((c >> 4) & 3) + 16 * (c >> 6) + (c & 15); }

// =============================== fused prep + frontend ===============================
// blocks < 1024 : frontend (computes its own weight folds in LDS)
// blocks >= 1024: weight fragment packing (prep)
__global__ __launch_bounds__(256) void prep_frontend(
    const float* __restrict__ x_feat, const int* __restrict__ acc_t,
    const float* __restrict__ de_w1, const float* __restrict__ de_b1,
    const float* __restrict__ de_w2, const float* __restrict__ de_b2,
    const float* __restrict__ embed, const float* __restrict__ comb_w,
    const float* __restrict__ comb_b,
    const float* __restrict__ w0ih, const float* __restrict__ w0hh,
    const float* __restrict__ b0ih, const float* __restrict__ b0hh,
    const float* __restrict__ w1ih, const float* __restrict__ w1hh,
    const float* __restrict__ b1ih, const float* __restrict__ b1hh,
    const float* __restrict__ dp_w1, const float* __restrict__ cp_w1,
    const float* __restrict__ pc_w1,
    const float* __restrict__ dp_w2, const float* __restrict__ cp_w2,
    const float* __restrict__ pc_w2,
    char* __restrict__ ws, unsigned short* __restrict__ feats)
{
  int tid = threadIdx.x;

  if (blockIdx.x >= 1024) {
    // -------- packing section --------
    unsigned short* wih0p = (unsigned short*)(ws + O_WIH0);
    unsigned short* whh0p = (unsigned short*)(ws + O_WHH0);
    unsigned short* wih1p = (unsigned short*)(ws + O_WIH1);
    unsigned short* whh1p = (unsigned short*)(ws + O_WHH1);
    float* b0p = (float*)(ws + O_B0);
    float* b1p = (float*)(ws + O_B1);
    unsigned short* w1f = (unsigned short*)(ws + O_W1F);
    float* dp2t = (float*)(ws + O_DP2T);
    float* cp2t = dp2t + 1024;
    float* pc2t = dp2t + 1536;

    const int U0 = 32768, U1 = 98304, U2 = 163840, U3 = 229376,
              U4 = 229888, U5 = 230400, U6 = 259072, U7 = 260096,
              U8 = 260608, U9 = 260736;

    for (int idx = (blockIdx.x - 1024) * 256 + tid; idx < U9; idx += 65536) {
      if (idx < U3) {  // LSTM MFMA fragment packing
        int u, Kin; const float* src; unsigned short* dst;
        if (idx < U0)      { u = idx;      Kin = 64;  src = w0ih; dst = wih0p; }
        else if (idx < U1) { u = idx - U0; Kin = 128; src = w0hh; dst = whh0p; }
        else if (idx < U2) { u = idx - U1; Kin = 128; src = w1ih; dst = wih1p; }
        else               { u = idx - U2; Kin = 128; src = w1hh; dst = whh1p; }
        int j = u & 7, l = (u >> 3) & 63, nt = (u >> 9) & 31, kt = u >> 14;
        int c = 16 * nt + (l & 15);
        int k = 32 * kt + 8 * (l >> 4) + j;
        dst[u] = f2b(src[orig_col(c) * Kin + k]);
      } else if (idx < U5) {  // permuted biases
        int u = idx - U3;
        if (u < 512) b0p[u] = b0ih[orig_col(u)] + b0hh[orig_col(u)];
        else { int c = u - 512; b1p[c] = b1ih[orig_col(c)] + b1hh[orig_col(c)]; }
      } else if (idx < U6) {  // head-W1 MFMA frags
        int u = idx - U5;
        int j = u & 7, l = (u >> 3) & 63, kt = (u >> 9) & 3, nt = u >> 11;
        int c = 16 * nt + (l & 15);
        int k = 32 * kt + 8 * (l >> 4) + j;
        float v;
        if (c < 128)      v = dp_w1[c * 128 + k];
        else if (c < 192) v = cp_w1[(c - 128) * 128 + k];
        else              v = pc_w1[(c - 192) * 128 + k];
        w1f[u] = f2b(v);
      }
      else if (idx < U7) { int u = idx - U6; int k = u >> 3, o = u & 7; dp2t[u] = dp_w2[o * 128 + k]; }
      else if (idx < U8) { int u = idx - U7; int k = u >> 3, o = u & 7; cp2t[u] = cp_w2[o * 64 + k]; }
      else               { int u = idx - U8; int k = u >> 2, o = u & 3; pc2t[u] = pc_w2[o * 32 + k]; }
    }
    return;
  }

  // -------- frontend section (folds computed locally; same formulas as before) --------
  __shared__ float sW1[256], sB1[32], sWa[2048], sBc[64], sE2T[1024];
  sW1[tid] = de_w1[tid];
  if (tid < 32) sB1[tid] = de_b1[tid];
  for (int i = tid; i < 2048; i += 256) {  // Wa[f][kk]
    int f = i >> 5, kk = i & 31;
    float a = 0.f;
    for (int f2 = 0; f2 < 64; f2++) a += comb_w[f * 80 + f2] * de_w2[f2 * 32 + kk];
    sWa[i] = a;
  }
  if (tid < 64) {  // bc[f]
    float a = comb_b[tid];
    for (int f2 = 0; f2 < 64; f2++) a += comb_w[tid * 80 + f2] * de_b2[f2];
    sBc[tid] = a;
  }
  for (int i = tid; i < 1024; i += 256) {  // sE2T[f*16+e]
    int f = i >> 4, e = i & 15;
    float a = 0.f;
    for (int j = 0; j < 16; j++) a += embed[e * 16 + j] * comb_w[f * 80 + 64 + j];
    sE2T[i] = a;
  }
  __syncthreads();

  int g = blockIdx.x * 256 + tid;  // g = b*32 + t
  f4v x0 = ((const f4v*)(x_feat + (size_t)g * 8))[0];
  f4v x1 = ((const f4v*)(x_feat + (size_t)g * 8))[1];
  float xs[8];
#pragma unroll
  for (int i = 0; i < 4; i++) { xs[i] = x0[i]; xs[4 + i] = x1[i]; }
  int at = acc_t[g];

  float r1[32];
#pragma unroll
  for (int kk = 0; kk < 32; kk++) {
    float a = sB1[kk];
#pragma unroll
    for (int i = 0; i < 8; i++) a += xs[i] * sW1[kk * 8 + i];
    r1[kk] = fmaxf(a, 0.f);
  }
  unsigned short* dst = feats + (size_t)g * 64;
  for (int j8 = 0; j8 < 8; j8++) {
    s8v pack;
#pragma unroll
    for (int jj = 0; jj < 8; jj++) {
      int j = j8 * 8 + jj;
      float a = sBc[j] + sE2T[j * 16 + at];
      const f4v* wr = (const f4v*)(sWa + j * 32);
#pragma unroll
      for (int k4 = 0; k4 < 8; k4++) {
        f4v wv = wr[k4];
        a += r1[4 * k4 + 0] * wv[0] + r1[4 * k4 + 1] * wv[1] +
             r1[4 * k4 + 2] * wv[2] + r1[4 * k4 + 3] * wv[3];
      }
      pack[jj] = (short)f2b(a);
    }
    *(s8v*)(dst + j8 * 8) = pack;
  }
}

// =============================== main LSTM (R8 skeleton + R5-proven pointwise) ===============================
template <int PASS>
DEV void run_pass(int tid, int blk,
                  const unsigned short* __restrict__ whhp,
                  const unsigned short* __restrict__ wihp,
                  const float* __restrict__ bp,
                  const unsigned short* __restrict__ inglob,
                  unsigned short* __restrict__ y0buf,
                  unsigned short* sWhh, unsigned short* sH0, unsigned short* sH1)
{
  constexpr int KIN = PASS ? 128 : 64;
  constexpr int NKT = KIN / 32;
  const int w = tid >> 6, l = tid & 63, l15 = l & 15, lhi = l >> 4;
  const int d = 16 * w + l15;

  // A-fragment element offset in the pass input for (t, mt, kt)
  auto aoff = [&](int t, int mt, int kt) -> size_t {
    int row = 16 * mt + l15;
    if constexpr (PASS == 0)
      return ((size_t)(blk * 32 + row) * 32 + t) * 64 + 32 * kt + 8 * lhi;
    else
      return (size_t)blk * 131072 + (size_t)t * 4096 + row * 128 + 32 * kt + 8 * lhi;
  };

  // prefetch t=0 input fragments
  s8v A0[2][NKT], A1[2][NKT];
#pragma unroll
  for (int mt = 0; mt < 2; mt++)
#pragma unroll
    for (int kt = 0; kt < NKT; kt++)
      A0[mt][kt] = *(const s8v*)(inglob + aoff(0, mt, kt));

  // stage whh fragments into LDS (linear, pre-packed)
  for (int i = tid; i < 8192; i += 512)
    *(s8v*)(sWhh + i * 8) = *(const s8v*)(whhp + i * 8);
  // zero h buffer 0
  { s8v z = {0, 0, 0, 0, 0, 0, 0, 0}; *(s8v*)(sH0 + tid * 8) = z; }

  // wih fragments -> registers
  s8v wf[NKT][4];
#pragma unroll
  for (int kt = 0; kt < NKT; kt++)
#pragma unroll
    for (int gg = 0; gg < 4; gg++)
      wf[kt][gg] = *(const s8v*)(wihp + ((size_t)(kt * 32 + 4 * w + gg) * 64 + l) * 8);

  // biases folded into exp2 pointwise constants (R5-proven)
  const float nbi2 = -bp[64 * w + l15] * LOG2E,
              nbf2 = -bp[64 * w + 16 + l15] * LOG2E,
              bg2  = 2.f * LOG2E * bp[64 * w + 32 + l15],
              nbo2 = -bp[64 * w + 48 + l15] * LOG2E;
  float cst[2][4] = {{0, 0, 0, 0}, {0, 0, 0, 0}};
  const f4v z4 = {0.f, 0.f, 0.f, 0.f};

  // coalesced y0 writeback geometry (un-swizzles h LDS blocks)
  const int yrow = tid >> 4, yq = tid & 15;
  const size_t ybase = (size_t)blk * 131072 + yrow * 128 + ((yq ^ (yrow & 7)) * 8);
  const int yldsb = yrow * 256 + yq * 16;  // byte offset into h buffer

  __syncthreads();

#define LSTM_STEP(T, AC, AN, HRD, HWR)                                          \
  {                                                                             \
    const int tn_ = (T) < 31 ? (T) + 1 : 31;                                    \
    _Pragma("unroll")                                                           \
    for (int mt = 0; mt < 2; mt++)                                              \
      _Pragma("unroll")                                                         \
      for (int kt = 0; kt < NKT; kt++)                                          \
        AN[mt][kt] = *(const s8v*)(inglob + aoff(tn_, mt, kt));                 \
    if (PASS == 0 && (T) > 0) {                                                 \
      s8v hv8 = *(const s8v*)((const char*)(HRD) + yldsb);                      \
      *(s8v*)(y0buf + ybase + (size_t)((T) - 1) * 4096) = hv8;                  \
    }                                                                           \
    f4v acc[2][4];                                                              \
    _Pragma("unroll")                                                           \
    for (int mt = 0; mt < 2; mt++)                                              \
      _Pragma("unroll")                                                         \
      for (int gg = 0; gg < 4; gg++)                                            \
        acc[mt][gg] = __builtin_amdgcn_mfma_f32_16x16x32_bf16(                  \
            AC[mt][0], wf[0][gg], z4, 0, 0, 0);                                 \
    _Pragma("unroll")                                                           \
    for (int kt = 1; kt < NKT; kt++)                                            \
      _Pragma("unroll")                                                         \
      for (int mt = 0; mt < 2; mt++)                                            \
        _Pragma("unroll")                                                       \
        for (int gg = 0; gg < 4; gg++)                                          \
          acc[mt][gg] = __builtin_amdgcn_mfma_f32_16x16x32_bf16(                \
              AC[mt][kt], wf[kt][gg], acc[mt][gg], 0, 0, 0);                    \
    _Pragma("unroll")                                                           \
    for (int kt = 0; kt < 4; kt++) {                                            \
      s8v bfr[4];                                                               \
      _Pragma("unroll")                                                         \
      for (int gg = 0; gg < 4; gg++)                                            \
        bfr[gg] = *(const s8v*)(sWhh + (size_t)((kt * 32 + 4 * w + gg) * 64 + l) * 8); \
      _Pragma("unroll")                                                         \
      for (int mt = 0; mt < 2; mt++) {                                          \
        int row = 16 * mt + l15;                                                \
        s8v ha = *(const s8v*)((const char*)(HRD) + row * 256 +                 \
                               ((kt * 64 + lhi * 16) ^ ((row & 7) << 4)));      \
        _Pragma("unroll")                                                       \
        for (int gg = 0; gg < 4; gg++)                                          \
          acc[mt][gg] = __builtin_amdgcn_mfma_f32_16x16x32_bf16(                \
              ha, bfr[gg], acc[mt][gg], 0, 0, 0);                               \
      }                                                                         \
    }                                                                           \
    _Pragma("unroll")                                                           \
    for (int mt = 0; mt < 2; mt++)                                              \
      _Pragma("unroll")                                                         \
      for (int rp = 0; rp < 2; rp++) {                                          \
        float h2[2];                                                            \
        _Pragma("unroll")                                                       \
        for (int rr = 0; rr < 2; rr++) {                                        \
          int r = 2 * rp + rr;                                                  \
          float xi = acc[mt][0][r], xf = acc[mt][1][r],                         \
                xg = acc[mt][2][r], xo = acc[mt][3][r];                         \
          float iv = __builtin_amdgcn_rcpf(1.f + exp2f(fmaf(xi, -LOG2E, nbi2)));\
          float fv = __builtin_amdgcn_rcpf(1.f + exp2f(fmaf(xf, -LOG2E, nbf2)));\
          float ov = __builtin_amdgcn_rcpf(1.f + exp2f(fmaf(xo, -LOG2E, nbo2)));\
          float eg = exp2f(fmaf(xg, 2.f * LOG2E, bg2));                         \
          float gv = fmaf(-2.f, __builtin_amdgcn_rcpf(eg + 1.f), 1.f);          \
          float cv = fmaf(fv, cst[mt][r], iv * gv);                             \
          cst[mt][r] = cv;                                                      \
          float ec = exp2f(cv * (2.f * LOG2E));                                 \
          float th = fmaf(-2.f, __builtin_amdgcn_rcpf(ec + 1.f), 1.f);          \
          h2[rr] = ov * th;                                                     \
        }                                                                       \
        unsigned pk;                                                            \
        asm("v_cvt_pk_bf16_f32 %0, %1, %2"                                      \
            : "=v"(pk) : "v"(h2[0]), "v"(h2[1]));                               \
        int rowA = 16 * mt + 4 * lhi + 2 * rp;                                  \
        int rowB = rowA + 1;                                                    \
        *(unsigned short*)((char*)(HWR) + rowA * 256 +                          \
                           ((d * 2) ^ ((rowA & 7) << 4))) = (unsigned short)pk; \
        *(unsigned short*)((char*)(HWR) + rowB * 256 +                          \
                           ((d * 2) ^ ((rowB & 7) << 4))) =                     \
            (unsigned short)(pk >> 16);                                         \
      }                                                                         \
    __syncthreads();                                                            \
  }

  for (int th = 0; th < 16; ++th) {
    LSTM_STEP(2 * th,     A0, A1, sH0, sH1)
    LSTM_STEP(2 * th + 1, A1, A0, sH1, sH0)
  }
#undef LSTM_STEP

  if (PASS == 0) {  // h(31) was written (step 31, odd) into sH0
    s8v hv8 = *(const s8v*)((const char*)sH0 + yldsb);
    *(s8v*)(y0buf + ybase + (size_t)31 * 4096) = hv8;
  }
}

// =============================== heads (MFMA epilogue, R8 verbatim) ===============================
DEV void heads_phase(int tid, int blk, char* pool, const char* ws,
                     const float* __restrict__ dp_b1, const float* __restrict__ dp_b2,
                     const float* __restrict__ cp_b1, const float* __restrict__ cp_b2,
                     const float* __restrict__ pc_b1, const float* __restrict__ pc_b2,
                     float* __restrict__ out)
{
  const int w = tid >> 6, l = tid & 63, l15 = l & 15, lhi = l >> 4;
  float* smid = (float*)(pool + P_HMID);   // [32][228] f32
  float* sw2  = (float*)(pool + P_HW2);    // 1664 f32
  float* spc  = (float*)(pool + P_HPC);    // 128 f32
  const char* sH0 = pool + P_H0;

  // stage w2 (small)
  for (int i = tid; i < 1664; i += 512) sw2[i] = ((const float*)(ws + O_DP2T))[i];

  if (w < 7) {  // waves 0..6 own n-tiles 2w, 2w+1 (14 tiles = 224 outputs)
    const unsigned short* w1f = (const unsigned short*)(ws + O_W1F);
    s8v bf[2][4];
#pragma unroll
    for (int nn = 0; nn < 2; nn++)
#pragma unroll
      for (int kt = 0; kt < 4; kt++)
        bf[nn][kt] = *(const s8v*)(w1f + (size_t)(((2 * w + nn) * 4 + kt) * 64 + l) * 8);

    const f4v z4 = {0.f, 0.f, 0.f, 0.f};
    f4v acc[2][2];  // [nn][mt]
#pragma unroll
    for (int kt = 0; kt < 4; kt++)
#pragma unroll
      for (int mt = 0; mt < 2; mt++) {
        int row = 16 * mt + l15;
        s8v ha = *(const s8v*)(sH0 + row * 256 + ((kt * 64 + lhi * 16) ^ ((row & 7) << 4)));
#pragma unroll
        for (int nn = 0; nn < 2; nn++)
          acc[nn][mt] = __builtin_amdgcn_mfma_f32_16x16x32_bf16(
              ha, bf[nn][kt], kt == 0 ? z4 : acc[nn][mt], 0, 0, 0);
      }

    // bias + relu + scatter to smid[row][c] (stride 228: 2-way banks max)
#pragma unroll
    for (int nn = 0; nn < 2; nn++) {
      int c = 16 * (2 * w + nn) + l15;
      float b1v = (c < 128) ? dp_b1[c] : ((c < 192) ? cp_b1[c - 128] : pc_b1[c - 192]);
#pragma unroll
      for (int mt = 0; mt < 2; mt++)
#pragma unroll
        for (int r = 0; r < 4; r++) {
          int row = 16 * mt + 4 * lhi + r;
          smid[row * 228 + c] = fmaxf(acc[nn][mt][r] + b1v, 0.f);
        }
    }
  }
  __syncthreads();

  // layer 2: 640 outputs
  for (int i = tid; i < 640; i += 512) {
    int row = i / 20, o = i - row * 20;
    const float* mr = smid + row * 228;
    if (o < 8) {
      float a = dp_b2[o];
      for (int k = 0; k < 128; k++) a += mr[k] * sw2[k * 8 + o];
      out[(size_t)(blk * 32 + row) * 20 + o] = a * 1e6f;
    } else if (o < 16) {
      int oo = o - 8; float a = cp_b2[oo];
      for (int k = 0; k < 64; k++) a += mr[128 + k] * sw2[1024 + k * 8 + oo];
      out[(size_t)(blk * 32 + row) * 20 + o] = sigf(a);
    } else {
      int oo = o - 16; float a = pc_b2[oo];
      for (int k = 0; k < 32; k++) a += mr[192 + k] * sw2[1536 + k * 4 + oo];
      spc[row * 4 + oo] = a;
    }
  }
  __syncthreads();

  if (tid < 32) {
    int row = tid;
    float v0 = spc[row * 4], v1 = spc[row * 4 + 1], v2 = spc[row * 4 + 2], v3 = spc[row * 4 + 3];
    float m = fmaxf(fmaxf(v0, v1), fmaxf(v2, v3));
    float e0 = __expf(v0 - m), e1 = __expf(v1 - m), e2 = __expf(v2 - m), e3 = __expf(v3 - m);
    float rs = __builtin_amdgcn_rcpf(e0 + e1 + e2 + e3);
    size_t base = (size_t)(blk * 32 + row) * 20 + 16;
    out[base] = e0 * rs; out[base + 1] = e1 * rs; out[base + 2] = e2 * rs; out[base + 3] = e3 * rs;
  }
}

__global__ __launch_bounds__(512, 2) void lstm_main(
    const char* __restrict__ ws_c, char* __restrict__ ws,
    const float* __restrict__ dp_b1, const float* __restrict__ dp_b2,
    const float* __restrict__ cp_b1, const float* __restrict__ cp_b2,
    const float* __restrict__ pc_b1, const float* __restrict__ pc_b2,
    float* __restrict__ out)
{
  __shared__ __align__(16) char pool[P_TOT];
  int tid = threadIdx.x, blk = blockIdx.x;
  unsigned short* sWhh = (unsigned short*)(pool + P_WHH);
  unsigned short* sH0  = (unsigned short*)(pool + P_H0);
  unsigned short* sH1  = (unsigned short*)(pool + P_H1);

  run_pass<0>(tid, blk,
              (const unsigned short*)(ws_c + O_WHH0), (const unsigned short*)(ws_c + O_WIH0),
              (const float*)(ws_c + O_B0),
              (const unsigned short*)(ws_c + O_FEATS),
              (unsigned short*)(ws + O_Y0),
              sWhh, sH0, sH1);
  __syncthreads();
  run_pass<1>(tid, blk,
              (const unsigned short*)(ws_c + O_WHH1), (const unsigned short*)(ws_c + O_WIH1),
              (const float*)(ws_c + O_B1),
              (const unsigned short*)(ws + O_Y0),
              nullptr,
              sWhh, sH0, sH1);
  __syncthreads();
  heads_phase(tid, blk, pool, ws_c, dp_b1, dp_b2, cp_b1, cp_b2, pc_b1, pc_b2, out);
}

// =============================== launch ===============================
extern "C" void kernel_launch(void* const* d_in, const int* in_sizes, int n_in,
                              void* d_out, int out_size, void* d_ws, size_t ws_size,
                              hipStream_t stream) {
  const float* x_feat = (const float*)d_in[0];
  const int*   acc_t  = (const int*)d_in[1];
  const float* de_w1 = (const float*)d_in[2],  *de_b1 = (const float*)d_in[3];
  const float* de_w2 = (const float*)d_in[4],  *de_b2 = (const float*)d_in[5];
  const float* embed = (const float*)d_in[6];
  const float* comb_w = (const float*)d_in[7], *comb_b = (const float*)d_in[8];
  const float* w0ih = (const float*)d_in[9],  *w0hh = (const float*)d_in[10];
  const float* b0ih = (const float*)d_in[11], *b0hh = (const float*)d_in[12];
  const float* w1ih = (const float*)d_in[13], *w1hh = (const float*)d_in[14];
  const float* b1ih = (const float*)d_in[15], *b1hh = (const float*)d_in[16];
  const float* dp_w1 = (const float*)d_in[17], *dp_b1 = (const float*)d_in[18];
  const float* dp_w2 = (const float*)d_in[19], *dp_b2 = (const float*)d_in[20];
  const float* cp_w1 = (const float*)d_in[21], *cp_b1 = (const float*)d_in[22];
  const float* cp_w2 = (const float*)d_in[23], *cp_b2 = (const float*)d_in[24];
  const float* pc_w1 = (const float*)d_in[25], *pc_b1 = (const float*)d_in[26];
  const float* pc_w2 = (const float*)d_in[27], *pc_b2 = (const float*)d_in[28];
  char* ws = (char*)d_ws;

  prep_frontend<<<1280, 256, 0, stream>>>(
      x_feat, acc_t, de_w1, de_b1, de_w2, de_b2, embed, comb_w, comb_b,
      w0ih, w0hh, b0ih, b0hh, w1ih, w1hh, b1ih, b1hh,
      dp_w1, cp_w1, pc_w1, dp_w2, cp_w2, pc_w2,
      ws, (unsigned short*)(ws + O_FEATS));

  lstm_main<<<256, 512, 0, stream>>>(
      ws, ws, dp_b1, dp_b2, cp_b1, cp_b2, pc_b1, pc_b2, (float*)d_out);
}

// Round 11
// 204.358 us; speedup vs baseline: 1.2670x; 1.2670x over previous
//
#include <hip/hip_runtime.h>
#include <hip/hip_bf16.h>

typedef short s8v __attribute__((ext_vector_type(8)));
typedef float f4v __attribute__((ext_vector_type(4)));

#define DEV __device__ __forceinline__

DEV unsigned short f2b(float f) {
  unsigned u = __builtin_bit_cast(unsigned, f);
  u += 0x7FFFu + ((u >> 16) & 1u);
  return (unsigned short)(u >> 16);
}
DEV float b2f(unsigned short s) {
  unsigned u = ((unsigned)s) << 16;
  return __builtin_bit_cast(float, u);
}
DEV float sigf(float x) { return __builtin_amdgcn_rcpf(1.f + __expf(-x)); }
DEV float tanhf_(float x) { return 1.f - 2.f * __builtin_amdgcn_rcpf(__expf(2.f * x) + 1.f); }

// ---------------- workspace layout (bytes, all 256-aligned) ----------------
#define O_WHH0  0u          // 131072  bf16 frag-packed whh0
#define O_WHH1  131072u     // 131072
#define O_WIH0  262144u     // 65536
#define O_WIH1  327680u     // 131072
#define O_B0    458752u     // 2048    f32 permuted bih0+bhh0
#define O_B1    460800u     // 2048
#define O_WA    462848u     // 8192    f32 folded comb_w[:, :64] @ de_w2  (64x32)
#define O_EMB2  471040u     // 4096    f32 embed @ comb_w[:,64:80]^T     (16x64)
#define O_BC    475136u     // 256     f32 comb_b + comb_w[:,:64]@de_b2  (64)
#define O_W1F   475392u     // 57344   bf16 head-W1 MFMA frags: [nt14][kt4][l64][j8]
#define O_DP2T  532736u     // 6656    f32 (dp2|cp2|pc2 contiguous)
#define O_FEATS 4733696u    // 33554432 bf16 feats [b*32+t][64] natural
#define O_Y0    38288128u   // 67108864 bf16 y0    [blk][t][row32][128]

// ---------------- LDS pool (147456 B) ----------------
// Passes: sWhh @ 0 (131072), sH0 @ 131072 (8192), sH1 @ 139264 (8192)
#define P_WHH   0
#define P_H0    131072
#define P_H1    139264
#define P_TOT   147456
// Heads phase (aliases 0..131072 after passes; sH0 @131072 preserved = h(31)):
#define P_HMID  0        // 29184  f32 smid[32][228]
#define P_HW2   29696    // 6656   f32 w2
#define P_HPC   36864    // 512    f32 pre-softmax

// Column permutation: reordered col c (0..511) -> orig gate-major row of W.
DEV int orig_col(int c) { return 128 * ((c >> 4) & 3) + 16 * (c >> 6) + (c & 15); }

// =============================== prep ===============================
__global__ void prep_kernel(
    const float* de_w1, const float* de_b1, const float* de_w2, const float* de_b2,
    const float* embed, const float* comb_w, const float* comb_b,
    const float* w0ih, const float* w0hh, const float* b0ih, const float* b0hh,
    const float* w1ih, const float* w1hh, const float* b1ih, const float* b1hh,
    const float* dp_w1, const float* dp_w2, const float* cp_w1, const float* cp_w2,
    const float* pc_w1, const float* pc_w2, char* ws)
{
  unsigned short* wih0p = (unsigned short*)(ws + O_WIH0);
  unsigned short* whh0p = (unsigned short*)(ws + O_WHH0);
  unsigned short* wih1p = (unsigned short*)(ws + O_WIH1);
  unsigned short* whh1p = (unsigned short*)(ws + O_WHH1);
  float* b0p = (float*)(ws + O_B0);
  float* b1p = (float*)(ws + O_B1);
  float* Wa  = (float*)(ws + O_WA);
  float* bc  = (float*)(ws + O_BC);
  float* em2 = (float*)(ws + O_EMB2);
  unsigned short* w1f = (unsigned short*)(ws + O_W1F);
  float* dp2t = (float*)(ws + O_DP2T);
  float* cp2t = dp2t + 1024;
  float* pc2t = dp2t + 1536;

  const int T0 = 32768, T1 = T0 + 65536, T2 = T1 + 65536, T3 = T2 + 65536,
            T4 = T3 + 512, T5 = T4 + 512, T6 = T5 + 2048, T7 = T6 + 64,
            T8 = T7 + 1024, T9 = T8 + 28672, T10 = T9 + 1024, T11 = T10 + 512,
            T12 = T11 + 128;

  for (int idx = blockIdx.x * 256 + threadIdx.x; idx < T12; idx += gridDim.x * 256) {
    if (idx < T3) {  // LSTM MFMA fragment packing
      int u, Kin; const float* src; unsigned short* dst;
      if (idx < T0)      { u = idx;      Kin = 64;  src = w0ih; dst = wih0p; }
      else if (idx < T1) { u = idx - T0; Kin = 128; src = w0hh; dst = whh0p; }
      else if (idx < T2) { u = idx - T1; Kin = 128; src = w1ih; dst = wih1p; }
      else               { u = idx - T2; Kin = 128; src = w1hh; dst = whh1p; }
      int j = u & 7, l = (u >> 3) & 63, nt = (u >> 9) & 31, kt = u >> 14;
      int c = 16 * nt + (l & 15);
      int k = 32 * kt + 8 * (l >> 4) + j;
      dst[u] = f2b(src[orig_col(c) * Kin + k]);
    } else if (idx < T5) {  // permuted biases
      int u = idx - T3;
      if (u < 512) b0p[u] = b0ih[orig_col(u)] + b0hh[orig_col(u)];
      else { int c = u - 512; b1p[c] = b1ih[orig_col(c)] + b1hh[orig_col(c)]; }
    } else if (idx < T6) {  // W_a[f][kk]
      int u = idx - T5, f = u >> 5, kk = u & 31;
      float a = 0.f;
      for (int f2 = 0; f2 < 64; f2++) a += comb_w[f * 80 + f2] * de_w2[f2 * 32 + kk];
      Wa[u] = a;
    } else if (idx < T7) {  // b_comb
      int f = idx - T6;
      float a = comb_b[f];
      for (int f2 = 0; f2 < 64; f2++) a += comb_w[f * 80 + f2] * de_b2[f2];
      bc[f] = a;
    } else if (idx < T8) {  // emb2[e][f]
      int u = idx - T7, e = u >> 6, f = u & 63;
      float a = 0.f;
      for (int j = 0; j < 16; j++) a += embed[e * 16 + j] * comb_w[f * 80 + 64 + j];
      em2[u] = a;
    } else if (idx < T9) {  // head-W1 MFMA frags
      int u = idx - T8;
      int j = u & 7, l = (u >> 3) & 63, kt = (u >> 9) & 3, nt = u >> 11;
      int c = 16 * nt + (l & 15);
      int k = 32 * kt + 8 * (l >> 4) + j;
      float v;
      if (c < 128)      v = dp_w1[c * 128 + k];
      else if (c < 192) v = cp_w1[(c - 128) * 128 + k];
      else              v = pc_w1[(c - 192) * 128 + k];
      w1f[u] = f2b(v);
    }
    else if (idx < T10)   { int u = idx - T9;  int k = u >> 3, o = u & 7; dp2t[u] = dp_w2[o * 128 + k]; }
    else if (idx < T11)   { int u = idx - T10; int k = u >> 3, o = u & 7; cp2t[u] = cp_w2[o * 64 + k]; }
    else                  { int u = idx - T11; int k = u >> 2, o = u & 3; pc2t[u] = pc_w2[o * 32 + k]; }
  }
}

// =============================== frontend ===============================
__global__ __launch_bounds__(256) void frontend_kernel(
    const float* __restrict__ x_feat, const int* __restrict__ acc_t,
    const float* __restrict__ de_w1, const float* __restrict__ de_b1,
    const char* __restrict__ ws, unsigned short* __restrict__ feats)
{
  __shared__ float sW1[256], sB1[32], sWa[2048], sBc[64], sE2T[1024];
  const float* Wa  = (const float*)(ws + O_WA);
  const float* bc  = (const float*)(ws + O_BC);
  const float* em2 = (const float*)(ws + O_EMB2);
  int tid = threadIdx.x;
  sW1[tid] = de_w1[tid];
  if (tid < 32) sB1[tid] = de_b1[tid];
  for (int i = tid; i < 2048; i += 256) sWa[i] = Wa[i];
  if (tid < 64) sBc[tid] = bc[tid];
  for (int i = tid; i < 1024; i += 256) sE2T[i] = em2[(i & 15) * 64 + (i >> 4)];
  __syncthreads();

  int g = blockIdx.x * 256 + tid;  // g = b*32 + t
  f4v x0 = ((const f4v*)(x_feat + (size_t)g * 8))[0];
  f4v x1 = ((const f4v*)(x_feat + (size_t)g * 8))[1];
  float xs[8];
#pragma unroll
  for (int i = 0; i < 4; i++) { xs[i] = x0[i]; xs[4 + i] = x1[i]; }
  int at = acc_t[g];

  float r1[32];
#pragma unroll
  for (int kk = 0; kk < 32; kk++) {
    float a = sB1[kk];
#pragma unroll
    for (int i = 0; i < 8; i++) a += xs[i] * sW1[kk * 8 + i];
    r1[kk] = fmaxf(a, 0.f);
  }
  unsigned short* dst = feats + (size_t)g * 64;
  for (int j8 = 0; j8 < 8; j8++) {
    s8v pack;
#pragma unroll
    for (int jj = 0; jj < 8; jj++) {
      int j = j8 * 8 + jj;
      float a = sBc[j] + sE2T[j * 16 + at];
      const f4v* wr = (const f4v*)(sWa + j * 32);
#pragma unroll
      for (int k4 = 0; k4 < 8; k4++) {
        f4v wv = wr[k4];
        a += r1[4 * k4 + 0] * wv[0] + r1[4 * k4 + 1] * wv[1] +
             r1[4 * k4 + 2] * wv[2] + r1[4 * k4 + 3] * wv[3];
      }
      pack[jj] = (short)f2b(a);
    }
    *(s8v*)(dst + j8 * 8) = pack;
  }
}

// =============================== main LSTM (K1 run_pass) ===============================
template <int PASS>
DEV void run_pass(int tid, int blk,
                  const unsigned short* __restrict__ whhp,
                  const unsigned short* __restrict__ wihp,
                  const float* __restrict__ bp,
                  const unsigned short* __restrict__ inglob,
                  unsigned short* __restrict__ y0buf,
                  unsigned short* sWhh, unsigned short* sH0, unsigned short* sH1)
{
  constexpr int KIN = PASS ? 128 : 64;
  constexpr int NKT = KIN / 32;
  const int w = tid >> 6, l = tid & 63, l15 = l & 15, lhi = l >> 4;
  const int d = 16 * w + l15;

  // A-fragment element offset in the pass input for (t, mt, kt)
  auto aoff = [&](int t, int mt, int kt) -> size_t {
    int row = 16 * mt + l15;
    if constexpr (PASS == 0)
      return ((size_t)(blk * 32 + row) * 32 + t) * 64 + 32 * kt + 8 * lhi;
    else
      return (size_t)blk * 131072 + (size_t)t * 4096 + row * 128 + 32 * kt + 8 * lhi;
  };

  // prefetch t=0 input fragments
  s8v A0[2][NKT], A1[2][NKT];
#pragma unroll
  for (int mt = 0; mt < 2; mt++)
#pragma unroll
    for (int kt = 0; kt < NKT; kt++)
      A0[mt][kt] = *(const s8v*)(inglob + aoff(0, mt, kt));

  // stage whh fragments into LDS (linear, pre-packed)
  for (int i = tid; i < 8192; i += 512)
    *(s8v*)(sWhh + i * 8) = *(const s8v*)(whhp + i * 8);
  // zero h buffer 0
  { s8v z = {0, 0, 0, 0, 0, 0, 0, 0}; *(s8v*)(sH0 + tid * 8) = z; }

  // wih fragments -> registers
  s8v wf[NKT][4];
#pragma unroll
  for (int kt = 0; kt < NKT; kt++)
#pragma unroll
    for (int gg = 0; gg < 4; gg++)
      wf[kt][gg] = *(const s8v*)(wihp + ((size_t)(kt * 32 + 4 * w + gg) * 64 + l) * 8);

  float bias_[4];
#pragma unroll
  for (int gg = 0; gg < 4; gg++) bias_[gg] = bp[64 * w + 16 * gg + l15];
  float cst[2][4] = {{0, 0, 0, 0}, {0, 0, 0, 0}};

  // coalesced y0 writeback geometry (un-swizzles h LDS blocks)
  const int yrow = tid >> 4, yq = tid & 15;
  const size_t ybase = (size_t)blk * 131072 + yrow * 128 + ((yq ^ (yrow & 7)) * 8);
  const int yldsb = yrow * 256 + yq * 16;  // byte offset into h buffer

  __syncthreads();

#define LSTM_STEP(T, AC, AN, HRD, HWR)                                          \
  {                                                                             \
    const int tn_ = (T) < 31 ? (T) + 1 : 31;                                    \
    _Pragma("unroll")                                                           \
    for (int mt = 0; mt < 2; mt++)                                              \
      _Pragma("unroll")                                                         \
      for (int kt = 0; kt < NKT; kt++)                                          \
        AN[mt][kt] = *(const s8v*)(inglob + aoff(tn_, mt, kt));                 \
    if (PASS == 0 && (T) > 0) {                                                 \
      s8v hv8 = *(const s8v*)((const char*)(HRD) + yldsb);                      \
      *(s8v*)(y0buf + ybase + (size_t)((T) - 1) * 4096) = hv8;                  \
    }                                                                           \
    f4v acc[2][4];                                                              \
    _Pragma("unroll")                                                           \
    for (int mt = 0; mt < 2; mt++)                                              \
      _Pragma("unroll")                                                         \
      for (int gg = 0; gg < 4; gg++)                                            \
        acc[mt][gg] = f4v{bias_[gg], bias_[gg], bias_[gg], bias_[gg]};          \
    _Pragma("unroll")                                                           \
    for (int kt = 0; kt < NKT; kt++)                                            \
      _Pragma("unroll")                                                         \
      for (int mt = 0; mt < 2; mt++)                                            \
        _Pragma("unroll")                                                       \
        for (int gg = 0; gg < 4; gg++)                                          \
          acc[mt][gg] = __builtin_amdgcn_mfma_f32_16x16x32_bf16(                \
              AC[mt][kt], wf[kt][gg], acc[mt][gg], 0, 0, 0);                    \
    _Pragma("unroll")                                                           \
    for (int kt = 0; kt < 4; kt++) {                                            \
      s8v bfr[4];                                                               \
      _Pragma("unroll")                                                         \
      for (int gg = 0; gg < 4; gg++)                                            \
        bfr[gg] = *(const s8v*)(sWhh + (size_t)((kt * 32 + 4 * w + gg) * 64 + l) * 8); \
      _Pragma("unroll")                                                         \
      for (int mt = 0; mt < 2; mt++) {                                          \
        int row = 16 * mt + l15;                                                \
        s8v ha = *(const s8v*)((const char*)(HRD) + row * 256 +                 \
                               ((kt * 64 + lhi * 16) ^ ((row & 7) << 4)));      \
        _Pragma("unroll")                                                       \
        for (int gg = 0; gg < 4; gg++)                                          \
          acc[mt][gg] = __builtin_amdgcn_mfma_f32_16x16x32_bf16(                \
              ha, bfr[gg], acc[mt][gg], 0, 0, 0);                               \
      }                                                                         \
    }                                                                           \
    _Pragma("unroll")                                                           \
    for (int mt = 0; mt < 2; mt++)                                              \
      _Pragma("unroll")                                                         \
      for (int r = 0; r < 4; r++) {                                             \
        float iv = sigf(acc[mt][0][r]);                                         \
        float fv = sigf(acc[mt][1][r]);                                         \
        float gv = tanhf_(acc[mt][2][r]);                                       \
        float ov = sigf(acc[mt][3][r]);                                         \
        float cv = fv * cst[mt][r] + iv * gv;                                   \
        cst[mt][r] = cv;                                                        \
        float hv = ov * tanhf_(cv);                                             \
        int row = 16 * mt + 4 * lhi + r;                                        \
        *(unsigned short*)((char*)(HWR) + row * 256 +                           \
                           ((d * 2) ^ ((row & 7) << 4))) = f2b(hv);             \
      }                                                                         \
    __syncthreads();                                                            \
  }

  for (int th = 0; th < 16; ++th) {
    LSTM_STEP(2 * th,     A0, A1, sH0, sH1)
    LSTM_STEP(2 * th + 1, A1, A0, sH1, sH0)
  }
#undef LSTM_STEP

  if (PASS == 0) {  // h(31) was written (step 31, odd) into sH0
    s8v hv8 = *(const s8v*)((const char*)sH0 + yldsb);
    *(s8v*)(y0buf + ybase + (size_t)31 * 4096) = hv8;
  }
}

// =============================== heads (MFMA epilogue) ===============================
// h(31) of pass 1 lives bf16-swizzled in sH0 — read A-fragments exactly like the
// recurrent MFMA does. B = W1 frags pre-packed in prep (no conflicted LDS reads).
DEV void heads_phase(int tid, int blk, char* pool, const char* ws,
                     const float* __restrict__ dp_b1, const float* __restrict__ dp_b2,
                     const float* __restrict__ cp_b1, const float* __restrict__ cp_b2,
                     const float* __restrict__ pc_b1, const float* __restrict__ pc_b2,
                     float* __restrict__ out)
{
  const int w = tid >> 6, l = tid & 63, l15 = l & 15, lhi = l >> 4;
  float* smid = (float*)(pool + P_HMID);   // [32][228] f32
  float* sw2  = (float*)(pool + P_HW2);    // 1664 f32
  float* spc  = (float*)(pool + P_HPC);    // 128 f32
  const char* sH0 = pool + P_H0;

  // stage w2 (small)
  for (int i = tid; i < 1664; i += 512) sw2[i] = ((const float*)(ws + O_DP2T))[i];

  if (w < 7) {  // waves 0..6 own n-tiles 2w, 2w+1 (14 tiles = 224 outputs)
    const unsigned short* w1f = (const unsigned short*)(ws + O_W1F);
    s8v bf[2][4];
#pragma unroll
    for (int nn = 0; nn < 2; nn++)
#pragma unroll
      for (int kt = 0; kt < 4; kt++)
        bf[nn][kt] = *(const s8v*)(w1f + (size_t)(((2 * w + nn) * 4 + kt) * 64 + l) * 8);

    const f4v z4 = {0.f, 0.f, 0.f, 0.f};
    f4v acc[2][2];  // [nn][mt]
#pragma unroll
    for (int kt = 0; kt < 4; kt++)
#pragma unroll
      for (int mt = 0; mt < 2; mt++) {
        int row = 16 * mt + l15;
        s8v ha = *(const s8v*)(sH0 + row * 256 + ((kt * 64 + lhi * 16) ^ ((row & 7) << 4)));
#pragma unroll
        for (int nn = 0; nn < 2; nn++)
          acc[nn][mt] = __builtin_amdgcn_mfma_f32_16x16x32_bf16(
              ha, bf[nn][kt], kt == 0 ? z4 : acc[nn][mt], 0, 0, 0);
      }

    // bias + relu + scatter to smid[row][c] (stride 228: 2-way banks max)
#pragma unroll
    for (int nn = 0; nn < 2; nn++) {
      int c = 16 * (2 * w + nn) + l15;
      float b1v = (c < 128) ? dp_b1[c] : ((c < 192) ? cp_b1[c - 128] : pc_b1[c - 192]);
#pragma unroll
      for (int mt = 0; mt < 2; mt++)
#pragma unroll
        for (int r = 0; r < 4; r++) {
          int row = 16 * mt + 4 * lhi + r;
          smid[row * 228 + c] = fmaxf(acc[nn][mt][r] + b1v, 0.f);
        }
    }
  }
  __syncthreads();

  // layer 2: 640 outputs
  for (int i = tid; i < 640; i += 512) {
    int row = i / 20, o = i - row * 20;
    const float* mr = smid + row * 228;
    if (o < 8) {
      float a = dp_b2[o];
      for (int k = 0; k < 128; k++) a += mr[k] * sw2[k * 8 + o];
      out[(size_t)(blk * 32 + row) * 20 + o] = a * 1e6f;
    } else if (o < 16) {
      int oo = o - 8; float a = cp_b2[oo];
      for (int k = 0; k < 64; k++) a += mr[128 + k] * sw2[1024 + k * 8 + oo];
      out[(size_t)(blk * 32 + row) * 20 + o] = sigf(a);
    } else {
      int oo = o - 16; float a = pc_b2[oo];
      for (int k = 0; k < 32; k++) a += mr[192 + k] * sw2[1536 + k * 4 + oo];
      spc[row * 4 + oo] = a;
    }
  }
  __syncthreads();

  if (tid < 32) {
    int row = tid;
    float v0 = spc[row * 4], v1 = spc[row * 4 + 1], v2 = spc[row * 4 + 2], v3 = spc[row * 4 + 3];
    float m = fmaxf(fmaxf(v0, v1), fmaxf(v2, v3));
    float e0 = __expf(v0 - m), e1 = __expf(v1 - m), e2 = __expf(v2 - m), e3 = __expf(v3 - m);
    float rs = __builtin_amdgcn_rcpf(e0 + e1 + e2 + e3);
    size_t base = (size_t)(blk * 32 + row) * 20 + 16;
    out[base] = e0 * rs; out[base + 1] = e1 * rs; out[base + 2] = e2 * rs; out[base + 3] = e3 * rs;
  }
}

__global__ __launch_bounds__(512, 2) void lstm_main(
    const char* __restrict__ ws_c, char* __restrict__ ws,
    const float* __restrict__ dp_b1, const float* __restrict__ dp_b2,
    const float* __restrict__ cp_b1, const float* __restrict__ cp_b2,
    const float* __restrict__ pc_b1, const float* __restrict__ pc_b2,
    float* __restrict__ out)
{
  __shared__ __align__(16) char pool[P_TOT];
  int tid = threadIdx.x, blk = blockIdx.x;
  unsigned short* sWhh = (unsigned short*)(pool + P_WHH);
  unsigned short* sH0  = (unsigned short*)(pool + P_H0);
  unsigned short* sH1  = (unsigned short*)(pool + P_H1);

  run_pass<0>(tid, blk,
              (const unsigned short*)(ws_c + O_WHH0), (const unsigned short*)(ws_c + O_WIH0),
              (const float*)(ws_c + O_B0),
              (const unsigned short*)(ws_c + O_FEATS),
              (unsigned short*)(ws + O_Y0),
              sWhh, sH0, sH1);
  __syncthreads();
  run_pass<1>(tid, blk,
              (const unsigned short*)(ws_c + O_WHH1), (const unsigned short*)(ws_c + O_WIH1),
              (const float*)(ws_c + O_B1),
              (const unsigned short*)(ws + O_Y0),
              nullptr,
              sWhh, sH0, sH1);
  __syncthreads();
  heads_phase(tid, blk, pool, ws_c, dp_b1, dp_b2, cp_b1, cp_b2, pc_b1, pc_b2, out);
}

// =============================== launch ===============================
extern "C" void kernel_launch(void* const* d_in, const int* in_sizes, int n_in,
                              void* d_out, int out_size, void* d_ws, size_t ws_size,
                              hipStream_t stream) {
  const float* x_feat = (const float*)d_in[0];
  const int*   acc_t  = (const int*)d_in[1];
  const float* de_w1 = (const float*)d_in[2],  *de_b1 = (const float*)d_in[3];
  const float* de_w2 = (const float*)d_in[4],  *de_b2 = (const float*)d_in[5];
  const float* embed = (const float*)d_in[6];
  const float* comb_w = (const float*)d_in[7], *comb_b = (const float*)d_in[8];
  const float* w0ih = (const float*)d_in[9],  *w0hh = (const float*)d_in[10];
  const float* b0ih = (const float*)d_in[11], *b0hh = (const float*)d_in[12];
  const float* w1ih = (const float*)d_in[13], *w1hh = (const float*)d_in[14];
  const float* b1ih = (const float*)d_in[15], *b1hh = (const float*)d_in[16];
  const float* dp_w1 = (const float*)d_in[17], *dp_b1 = (const float*)d_in[18];
  const float* dp_w2 = (const float*)d_in[19], *dp_b2 = (const float*)d_in[20];
  const float* cp_w1 = (const float*)d_in[21], *cp_b1 = (const float*)d_in[22];
  const float* cp_w2 = (const float*)d_in[23], *cp_b2 = (const float*)d_in[24];
  const float* pc_w1 = (const float*)d_in[25], *pc_b1 = (const float*)d_in[26];
  const float* pc_w2 = (const float*)d_in[27], *pc_b2 = (const float*)d_in[28];
  char* ws = (char*)d_ws;

  prep_kernel<<<256, 256, 0, stream>>>(
      de_w1, de_b1, de_w2, de_b2, embed, comb_w, comb_b,
      w0ih, w0hh, b0ih, b0hh, w1ih, w1hh, b1ih, b1hh,
      dp_w1, dp_w2, cp_w1, cp_w2, pc_w1, pc_w2, ws);

  frontend_kernel<<<1024, 256, 0, stream>>>(
      x_feat, acc_t, de_w1, de_b1, ws, (unsigned short*)(ws + O_FEATS));

  lstm_main<<<256, 512, 0, stream>>>(
      ws, ws, dp_b1, dp_b2, cp_b1, cp_b2, pc_b1, pc_b2, (float*)d_out);
}